// Round 9
// baseline (373.824 us; speedup 1.0000x reference)
//
#include <hip/hip_runtime.h>
#include <hip/hip_bf16.h>

#define B_   4
#define S_   2048
#define D_   1024
#define H_   16
#define DK_  64
#define NTOK 8192

typedef __bf16 bf16_t;
typedef __bf16 bf16x8 __attribute__((ext_vector_type(8)));
typedef __bf16 bf16x4 __attribute__((ext_vector_type(4)));
typedef __bf16 bf16x2 __attribute__((ext_vector_type(2)));
typedef float  f32x4  __attribute__((ext_vector_type(4)));
typedef float  f32x16 __attribute__((ext_vector_type(16)));
typedef unsigned u32x4 __attribute__((ext_vector_type(4)));
typedef int    i32x2  __attribute__((ext_vector_type(2)));

__device__ __forceinline__ void gll16(const void* g, void* l) {
  __builtin_amdgcn_global_load_lds(
      (const __attribute__((address_space(1))) void*)g,
      (__attribute__((address_space(3))) void*)l,
      16, 0, 0);
}

__device__ __forceinline__ f32x4 mfma32(bf16x8 a, bf16x8 b, f32x4 c) {
  return __builtin_amdgcn_mfma_f32_16x16x32_bf16(a, b, c, 0, 0, 0);
}

__device__ __forceinline__ f32x16 mfma32x32(bf16x8 a, bf16x8 b, f32x16 c) {
#if defined(__HIP_DEVICE_COMPILE__)
  return __builtin_amdgcn_mfma_f32_32x32x16_bf16(a, b, c, 0, 0, 0);
#else
  (void)a; (void)b;
  return c;
#endif
}

// Single-instruction v_exp_f32 (exp2f without -ffast-math takes the OCML
// precise path we don't need — P only has bf16 precision anyway).
__device__ __forceinline__ float fast_exp2(float x) {
#if defined(__HIP_DEVICE_COMPILE__) && __has_builtin(__builtin_amdgcn_exp2f)
  return __builtin_amdgcn_exp2f(x);
#else
  return exp2f(x);
#endif
}

__device__ __forceinline__ f32x16 zero16() {
  f32x16 z;
#pragma unroll
  for (int i = 0; i < 16; ++i) z[i] = 0.f;
  return z;
}

// pack two f32 -> one u32 of 2x bf16 (compiler emits v_cvt_pk_bf16_f32)
__device__ __forceinline__ unsigned pkbf(float lo, float hi) {
  bf16x2 t;
  t[0] = (bf16_t)lo;
  t[1] = (bf16_t)hi;
  return __builtin_bit_cast(unsigned, t);
}

// v_permlane32_swap_b32: exchanges vdst-high with vsrc-low.
// After plswap(x, y):  x = {lanes<32: x_old, lanes>=32: y_old[l-32]}  (both lows)
//                      y = {lanes<32: x_old[l+32], lanes>=32: y_old}  (both highs)
__device__ __forceinline__ void plswap(unsigned &x, unsigned &y) {
#if defined(__HIP_DEVICE_COMPILE__)
  i32x2 r = __builtin_amdgcn_permlane32_swap((int)x, (int)y, false, false);
  x = (unsigned)r[0];
  y = (unsigned)r[1];
#endif
}

// From one 32x32 S^T accumulator (rows = 32 kv, cols = 32 q; per-lane reg r
// holds kv_local = (r&3)+8*(r>>2)+4*hi for q = lane&31), produce the two
// K=16 B-operand fragments of P (p0: kv 0..15, p1: kv 16..31), exp2 applied.
__device__ __forceinline__ void build_pa(const f32x16 s, bf16x8 &p0, bf16x8 &p1) {
  unsigned A0 = pkbf(fast_exp2(s[0]),  fast_exp2(s[1]));
  unsigned A1 = pkbf(fast_exp2(s[2]),  fast_exp2(s[3]));
  unsigned B0 = pkbf(fast_exp2(s[4]),  fast_exp2(s[5]));
  unsigned B1 = pkbf(fast_exp2(s[6]),  fast_exp2(s[7]));
  unsigned C0 = pkbf(fast_exp2(s[8]),  fast_exp2(s[9]));
  unsigned C1 = pkbf(fast_exp2(s[10]), fast_exp2(s[11]));
  unsigned D0 = pkbf(fast_exp2(s[12]), fast_exp2(s[13]));
  unsigned D1 = pkbf(fast_exp2(s[14]), fast_exp2(s[15]));
  plswap(A0, B0);  // A0 -> word0 (k = hi*8+{0,1}), B0 -> word2 (k = hi*8+{4,5})
  plswap(A1, B1);  // A1 -> word1,                  B1 -> word3
  plswap(C0, D0);
  plswap(C1, D1);
  u32x4 lo = {A0, A1, B0, B1};
  u32x4 hi = {C0, C1, D0, D1};
  p0 = __builtin_bit_cast(bf16x8, lo);
  p1 = __builtin_bit_cast(bf16x8, hi);
}

// ---------------------------------------------------------------------------
// Kernel 1: transpose the 4 weight matrices to bf16 [z][n][k].
// ---------------------------------------------------------------------------
__global__ __launch_bounds__(256) void prep_weights(
    const float* __restrict__ wq, const float* __restrict__ wk,
    const float* __restrict__ wv, const float* __restrict__ wo,
    bf16_t* __restrict__ wtHi) {
  const int z = blockIdx.z;
  const float* W = (z == 0) ? wq : (z == 1) ? wk : (z == 2) ? wv : wo;
  const int k0 = blockIdx.x * 64;
  const int n0 = blockIdx.y * 64;
  const int t = threadIdx.x;
  __shared__ float T[64][65];
#pragma unroll
  for (int rr = 0; rr < 4; ++rr) {
    int row = rr * 16 + (t >> 4);
    int cc = (t & 15) * 4;
    const float4 v = *(const float4*)&W[(size_t)(k0 + row) * D_ + n0 + cc];
    T[row][cc + 0] = v.x; T[row][cc + 1] = v.y;
    T[row][cc + 2] = v.z; T[row][cc + 3] = v.w;
  }
  __syncthreads();
  const int n = t >> 2;
  const int kc = (t & 3) * 16;
  bf16x8 h0, h1;
#pragma unroll
  for (int j = 0; j < 16; ++j) {
    float vv = T[kc + j][n];
    if (j < 8) h0[j] = (bf16_t)vv;
    else       h1[j - 8] = (bf16_t)vv;
  }
  size_t ofs = (size_t)z * 1048576 + (size_t)(n0 + n) * D_ + k0 + kc;
  *(bf16x8*)&wtHi[ofs] = h0; *(bf16x8*)&wtHi[ofs + 8] = h1;
}

// ---------------------------------------------------------------------------
// Kernel 2: QKV projection GEMM, FUSED fp32->bf16 A conversion, BK=64,
// T14-pipelined: per iteration, A(kt+1) f32 loads and W(kt+1) gll16 are
// ISSUED before the MFMA phase (latency hides under ~1000 cyc of matrix
// work), and the dependent cvt_pk + ds_write land after it, into the other
// LDS buffer. One barrier per iteration. R8's unpipelined version measured
// MfmaUtil 16.9% / 122 us — pure exposed-staging latency; this attacks it.
// ---------------------------------------------------------------------------
__global__ __launch_bounds__(256) void gemm_qkv_fused(
    const float* __restrict__ Aq, const float* __restrict__ Ak,
    const float* __restrict__ Av,
    const float* __restrict__ bq, const float* __restrict__ bk,
    const float* __restrict__ bv,
    const bf16_t* __restrict__ wtHi, bf16_t* __restrict__ outQKV) {
  const int z = blockIdx.z;
  const float* A    = (z == 0) ? Aq : (z == 1) ? Ak : Av;
  const float* bias = (z == 0) ? bq : (z == 1) ? bk : bv;
  const bf16_t* WHi = wtHi + (size_t)z * 1048576;
  bf16_t* Out = outQKV + (size_t)z * 8388608;

  const int row0 = blockIdx.x * 128;
  const int col0 = blockIdx.y * 128;
  const int t = threadIdx.x;
  const int w = t >> 6, L = t & 63;
  const int m = L & 15, g = L >> 4;

  __shared__ __align__(16) bf16_t As2[2][128 * 64];
  __shared__ __align__(16) bf16_t Whi_s[2][128 * 64];

  f32x4 acc[4][4];
#pragma unroll
  for (int i = 0; i < 4; ++i)
#pragma unroll
    for (int j = 0; j < 4; ++j) acc[i][j] = (f32x4){0.f, 0.f, 0.f, 0.f};

  const int aw0 = (w & 1) * 64;
  const int bw0 = (w >> 1) * 64;

  // staging: 1024 chunks of 8 elems per tile; thread t covers chunks {i*256+t}.
  int srow[4], scol[4];
#pragma unroll
  for (int i = 0; i < 4; ++i) {
    int slot = i * 256 + t;
    srow[i] = slot >> 3;
    scol[i] = (slot & 7) ^ (srow[i] & 7);
  }

  f32x4 rA[8];  // next-tile A values in flight (statically indexed)

  // ---- prologue: stage tile 0 into buffer 0 ----
#pragma unroll
  for (int i = 0; i < 4; ++i) {
    const float* src = &A[(size_t)(row0 + srow[i]) * D_ + scol[i] * 8];
    rA[2 * i]     = *(const f32x4*)src;
    rA[2 * i + 1] = *(const f32x4*)(src + 4);
  }
#pragma unroll
  for (int i = 0; i < 4; ++i) {
    u32x4 pk = {pkbf(rA[2 * i][0], rA[2 * i][1]),
                pkbf(rA[2 * i][2], rA[2 * i][3]),
                pkbf(rA[2 * i + 1][0], rA[2 * i + 1][1]),
                pkbf(rA[2 * i + 1][2], rA[2 * i + 1][3])};
    *(u32x4*)&As2[0][(i * 256 + t) * 8] = pk;
  }
#pragma unroll
  for (int i = 0; i < 4; ++i)
    gll16(&WHi[(size_t)(col0 + srow[i]) * D_ + scol[i] * 8],
          &Whi_s[0][i * 2048 + w * 512]);
  __syncthreads();

  for (int kt = 0; kt < 16; ++kt) {
    const int c = kt & 1;
    const bool more = (kt < 15);
    const int k1 = (kt + 1) * 64;

    // issue next-tile staging EARLY: A loads to regs, W gll16 to buf c^1
    if (more) {
#pragma unroll
      for (int i = 0; i < 4; ++i) {
        const float* src = &A[(size_t)(row0 + srow[i]) * D_ + k1 + scol[i] * 8];
        rA[2 * i]     = *(const f32x4*)src;
        rA[2 * i + 1] = *(const f32x4*)(src + 4);
      }
#pragma unroll
      for (int i = 0; i < 4; ++i)
        gll16(&WHi[(size_t)(col0 + srow[i]) * D_ + k1 + scol[i] * 8],
              &Whi_s[c ^ 1][i * 2048 + w * 512]);
    }

    // MFMA phase on buffer c (loads above stay in flight underneath)
    const bf16_t* as_b = &As2[c][0];
    const bf16_t* ws_b = &Whi_s[c][0];
#pragma unroll
    for (int kh = 0; kh < 2; ++kh) {
      bf16x8 af[4], wh[4];
#pragma unroll
      for (int it = 0; it < 4; ++it) {
        int row = aw0 + it * 16 + m;
        int sl = ((kh * 4 + g) ^ (m & 7)) * 8;
        af[it] = *(const bf16x8*)&as_b[row * 64 + sl];
      }
#pragma unroll
      for (int jt = 0; jt < 4; ++jt) {
        int n = bw0 + jt * 16 + m;
        int sl = ((kh * 4 + g) ^ (m & 7)) * 8;
        wh[jt] = *(const bf16x8*)&ws_b[n * 64 + sl];
      }
#pragma unroll
      for (int it = 0; it < 4; ++it)
#pragma unroll
        for (int jt = 0; jt < 4; ++jt)
          acc[it][jt] = mfma32(af[it], wh[jt], acc[it][jt]);
    }

    // write-late: cvt + ds_write of the prefetched A into buf c^1
    if (more) {
#pragma unroll
      for (int i = 0; i < 4; ++i) {
        u32x4 pk = {pkbf(rA[2 * i][0], rA[2 * i][1]),
                    pkbf(rA[2 * i][2], rA[2 * i][3]),
                    pkbf(rA[2 * i + 1][0], rA[2 * i + 1][1]),
                    pkbf(rA[2 * i + 1][2], rA[2 * i + 1][3])};
        *(u32x4*)&As2[c ^ 1][(i * 256 + t) * 8] = pk;
      }
    }
    __syncthreads();
  }

#pragma unroll
  for (int jt = 0; jt < 4; ++jt) {
    int col = col0 + bw0 + jt * 16 + m;
    float bcol = bias[col];
    int h = col >> 6, d = col & 63;
#pragma unroll
    for (int it = 0; it < 4; ++it) {
      if (z != 2) {
#pragma unroll
        for (int r = 0; r < 4; ++r) {
          int row = row0 + aw0 + it * 16 + g * 4 + r;
          int b = row >> 11, s = row & 2047;
          Out[((size_t)((b * H_ + h) * S_ + s)) * DK_ + d] =
              (bf16_t)(acc[it][jt][r] + bcol);
        }
      } else {
        int row = row0 + aw0 + it * 16 + g * 4;
        int b = row >> 11, s = row & 2047;
        bf16x4 p4;
#pragma unroll
        for (int r = 0; r < 4; ++r) p4[r] = (bf16_t)(acc[it][jt][r] + bcol);
        *(bf16x4*)&Out[((size_t)((b * H_ + h) * DK_ + d)) * S_ + s] = p4;
      }
    }
  }
}

// ---------------------------------------------------------------------------
// Kernel 3: flash attention on 32x32x16 MFMA (T12 structure) — measured-best
// config (86.0 us R7 / 83.1 us R1 bench): 4-wave/256-thread blocks,
// single-buffered 16 KB LDS, no dbuf, no XCD swizzle. Three scheduling
// variants (dbuf+swizzle, T15 deferred-PV, 2-wave blocks) all measured
// slower; this is the empirical optimum of the family.
// Q pre-scaled by 0.125*log2(e) so scores exit QK^T in log2 domain; raw
// v_exp_f32; P fragments assembled in-register via cvt_pk + permlane32_swap;
// denominator on the MFMA pipe via an all-ones A operand; PV computes O^T
// with V^T as the A operand so the per-lane output is row-major in d.
// ---------------------------------------------------------------------------
__global__ __launch_bounds__(256, 2) void attn(
    const bf16_t* __restrict__ Qh, const bf16_t* __restrict__ Kh,
    const bf16_t* __restrict__ VhT, bf16_t* __restrict__ Ohi) {
  const int bh = blockIdx.y;
  const int q0 = blockIdx.x * 128;
  const int t = threadIdx.x, w = t >> 6;
  const int lane = t & 63;
  const int lo5 = lane & 31, hi = lane >> 5;

  __shared__ __align__(16) bf16_t Ks[64 * 64];  // [kv][d], xor-swizzled chunks
  __shared__ __align__(16) bf16_t Vt[64 * 64];  // [d][kv], xor-swizzled chunks

  const size_t qbase = (size_t)bh * S_ * DK_;
  const size_t vbase = (size_t)bh * DK_ * S_;

  // Q fragments (B-operand): lane holds Q[q = qrow][dk = ks*16 + hi*8 + j],
  // pre-scaled by (1/sqrt(DK)) * log2(e)
  const int qrow = q0 + w * 32 + lo5;
  bf16x8 qf[4];
#pragma unroll
  for (int ks = 0; ks < 4; ++ks) {
    bf16x8 v = *(const bf16x8*)&Qh[qbase + (size_t)qrow * DK_ + ks * 16 + hi * 8];
#pragma unroll
    for (int j = 0; j < 8; ++j) v[j] = (bf16_t)(0.18033688f * (float)v[j]);
    qf[ks] = v;
  }

  bf16x8 ones;
#pragma unroll
  for (int j = 0; j < 8; ++j) ones[j] = (bf16_t)1.f;

  // Per-lane LDS element offsets, shared by Ks and Vt reads (rows 0..31;
  // +2048 elements reaches rows 32..63, same swizzle since 32 ≡ 0 mod 8).
  int offs[4];
#pragma unroll
  for (int ks = 0; ks < 4; ++ks)
    offs[ks] = lo5 * 64 + (((ks * 2 + hi) ^ (lo5 & 7)) * 8);

  f32x16 oacc0 = zero16(), oacc1 = zero16(), lacc = zero16();

  for (int kv0 = 0; kv0 < S_; kv0 += 64) {
#pragma unroll
    for (int rr = 0; rr < 2; ++rr) {
      int lin16 = rr * 256 + t;
      int rrow = lin16 >> 3;
      int c = (lin16 & 7) ^ (rrow & 7);
      gll16(&Kh[qbase + (size_t)(kv0 + rrow) * DK_ + c * 8], &Ks[rr * 2048 + w * 512]);
      gll16(&VhT[vbase + (size_t)rrow * S_ + kv0 + c * 8], &Vt[rr * 2048 + w * 512]);
    }
    __syncthreads();

    // S^T (log2 domain): two 32x32 tiles, rows = kv, cols = q
    f32x16 sc0 = zero16(), sc1 = zero16();
#pragma unroll
    for (int ks = 0; ks < 4; ++ks) {
      bf16x8 k0 = *(const bf16x8*)&Ks[offs[ks]];
      bf16x8 k1 = *(const bf16x8*)&Ks[offs[ks] + 2048];
      sc0 = mfma32x32(k0, qf[ks], sc0);
      sc1 = mfma32x32(k1, qf[ks], sc1);
    }

    // P = 2^S packed to bf16 B-operand fragments (kv 16 per fragment)
    bf16x8 pa0, pa1, pa2, pa3;
    build_pa(sc0, pa0, pa1);
    build_pa(sc1, pa2, pa3);

    // PV + denominator, all on the MFMA pipe
#pragma unroll
    for (int ks = 0; ks < 4; ++ks) {
      bf16x8 pb = (ks == 0) ? pa0 : (ks == 1) ? pa1 : (ks == 2) ? pa2 : pa3;
      lacc = mfma32x32(ones, pb, lacc);
      bf16x8 v0 = *(const bf16x8*)&Vt[offs[ks]];
      bf16x8 v1 = *(const bf16x8*)&Vt[offs[ks] + 2048];
      oacc0 = mfma32x32(v0, pb, oacc0);
      oacc1 = mfma32x32(v1, pb, oacc1);
    }
    __syncthreads();
  }

  // epilogue: every lacc row is the full column sum — no reduction needed.
  // oacc reg r holds O^T[d][q]: q = lane&31, d = (r>>2)*8 + hi*4 + (r&3).
  const int b = bh >> 4, h = bh & 15;
  const float inv = 1.f / lacc[0];
  const size_t rowofs = ((size_t)(b * S_ + qrow)) * D_ + h * DK_;
#pragma unroll
  for (int rg = 0; rg < 4; ++rg) {
    bf16x4 o0, o1;
#pragma unroll
    for (int j = 0; j < 4; ++j) {
      o0[j] = (bf16_t)(oacc0[rg * 4 + j] * inv);
      o1[j] = (bf16_t)(oacc1[rg * 4 + j] * inv);
    }
    *(bf16x4*)&Ohi[rowofs + rg * 8 + hi * 4] = o0;
    *(bf16x4*)&Ohi[rowofs + 32 + rg * 8 + hi * 4] = o1;
  }
}

// ---------------------------------------------------------------------------
// Kernel 4: output projection, single-term bf16, BK=64.
// ---------------------------------------------------------------------------
__global__ __launch_bounds__(256) void gemm_out(
    const bf16_t* __restrict__ Ahi, const bf16_t* __restrict__ wtHi,
    const float* __restrict__ bias, float* __restrict__ Out) {
  const bf16_t* WHi = wtHi + (size_t)3 * 1048576;
  const int row0 = blockIdx.x * 128;
  const int col0 = blockIdx.y * 128;
  const int t = threadIdx.x;
  const int w = t >> 6, L = t & 63;
  const int m = L & 15, g = L >> 4;

  __shared__ __align__(16) bf16_t Ahi_s[128 * 64];
  __shared__ __align__(16) bf16_t Whi_s[128 * 64];

  f32x4 acc[4][4];
#pragma unroll
  for (int i = 0; i < 4; ++i)
#pragma unroll
    for (int j = 0; j < 4; ++j) acc[i][j] = (f32x4){0.f, 0.f, 0.f, 0.f};

  const int aw0 = (w & 1) * 64;
  const int bw0 = (w >> 1) * 64;

  int srow[4], scol[4];
#pragma unroll
  for (int i = 0; i < 4; ++i) {
    int slot = i * 256 + t;
    srow[i] = slot >> 3;
    scol[i] = (slot & 7) ^ (srow[i] & 7);
  }

  for (int kt = 0; kt < 16; ++kt) {
    const int k0 = kt * 64;
#pragma unroll
    for (int i = 0; i < 4; ++i) {
      gll16(&Ahi[(size_t)(row0 + srow[i]) * D_ + k0 + scol[i] * 8],
            &Ahi_s[i * 2048 + w * 512]);
      gll16(&WHi[(size_t)(col0 + srow[i]) * D_ + k0 + scol[i] * 8],
            &Whi_s[i * 2048 + w * 512]);
    }
    __syncthreads();

#pragma unroll
    for (int kh = 0; kh < 2; ++kh) {
      bf16x8 ah[4], wh[4];
#pragma unroll
      for (int it = 0; it < 4; ++it) {
        int row = aw0 + it * 16 + m;
        int sl = ((kh * 4 + g) ^ (m & 7)) * 8;
        ah[it] = *(const bf16x8*)&Ahi_s[row * 64 + sl];
      }
#pragma unroll
      for (int jt = 0; jt < 4; ++jt) {
        int n = bw0 + jt * 16 + m;
        int sl = ((kh * 4 + g) ^ (m & 7)) * 8;
        wh[jt] = *(const bf16x8*)&Whi_s[n * 64 + sl];
      }
#pragma unroll
      for (int it = 0; it < 4; ++it)
#pragma unroll
        for (int jt = 0; jt < 4; ++jt)
          acc[it][jt] = mfma32(ah[it], wh[jt], acc[it][jt]);
    }
    __syncthreads();
  }
#pragma unroll
  for (int jt = 0; jt < 4; ++jt) {
    int col = col0 + bw0 + jt * 16 + m;
    float bcol = bias[col];
#pragma unroll
    for (int it = 0; it < 4; ++it)
#pragma unroll
      for (int r = 0; r < 4; ++r) {
        int row = row0 + aw0 + it * 16 + g * 4 + r;
        Out[(size_t)row * D_ + col] = acc[it][jt][r] + bcol;
      }
  }
}

// ---------------------------------------------------------------------------
extern "C" void kernel_launch(void* const* d_in, const int* in_sizes, int n_in,
                              void* d_out, int out_size, void* d_ws, size_t ws_size,
                              hipStream_t stream) {
  const float* q  = (const float*)d_in[0];
  const float* k  = (const float*)d_in[1];
  const float* v  = (const float*)d_in[2];
  const float* wq = (const float*)d_in[3];
  const float* bq = (const float*)d_in[4];
  const float* wk = (const float*)d_in[5];
  const float* bk = (const float*)d_in[6];
  const float* wv = (const float*)d_in[7];
  const float* bv = (const float*)d_in[8];
  const float* wo = (const float*)d_in[9];
  const float* bo = (const float*)d_in[10];
  float* out = (float*)d_out;

  // Workspace: 72 MB total.
  char* ws = (char*)d_ws;
  bf16_t* wtHi = (bf16_t*)(ws);                      // 8 MB
  bf16_t* QKVh = (bf16_t*)(ws + (8ull << 20));       // 48 MB (Qh, Kh, VhT)
  bf16_t* Ohi  = (bf16_t*)(ws + (56ull << 20));      // 16 MB

  hipLaunchKernelGGL(prep_weights, dim3(16, 16, 4), dim3(256), 0, stream,
                     wq, wk, wv, wo, wtHi);
  hipLaunchKernelGGL(gemm_qkv_fused, dim3(64, 8, 3), dim3(256), 0, stream,
                     q, k, v, bq, bk, bv, wtHi, QKVh);
  hipLaunchKernelGGL(attn, dim3(16, 64), dim3(256), 0, stream,
                     QKVh, QKVh + 8388608, QKVh + 16777216, Ohi);
  hipLaunchKernelGGL(gemm_out, dim3(64, 8), dim3(256), 0, stream,
                     Ohi, wtHi, bo, out);
}

// Round 10
// 339.665 us; speedup vs baseline: 1.1006x; 1.1006x over previous
//
#include <hip/hip_runtime.h>
#include <hip/hip_bf16.h>

#define B_   4
#define S_   2048
#define D_   1024
#define H_   16
#define DK_  64
#define NTOK 8192

typedef __bf16 bf16_t;
typedef __bf16 bf16x8 __attribute__((ext_vector_type(8)));
typedef __bf16 bf16x4 __attribute__((ext_vector_type(4)));
typedef __bf16 bf16x2 __attribute__((ext_vector_type(2)));
typedef float  f32x4  __attribute__((ext_vector_type(4)));
typedef float  f32x16 __attribute__((ext_vector_type(16)));
typedef unsigned u32x4 __attribute__((ext_vector_type(4)));
typedef int    i32x2  __attribute__((ext_vector_type(2)));

__device__ __forceinline__ void gll16(const void* g, void* l) {
  __builtin_amdgcn_global_load_lds(
      (const __attribute__((address_space(1))) void*)g,
      (__attribute__((address_space(3))) void*)l,
      16, 0, 0);
}

__device__ __forceinline__ f32x4 mfma32(bf16x8 a, bf16x8 b, f32x4 c) {
  return __builtin_amdgcn_mfma_f32_16x16x32_bf16(a, b, c, 0, 0, 0);
}

__device__ __forceinline__ f32x16 mfma32x32(bf16x8 a, bf16x8 b, f32x16 c) {
#if defined(__HIP_DEVICE_COMPILE__)
  return __builtin_amdgcn_mfma_f32_32x32x16_bf16(a, b, c, 0, 0, 0);
#else
  (void)a; (void)b;
  return c;
#endif
}

// Single-instruction v_exp_f32 (exp2f without -ffast-math takes the OCML
// precise path we don't need — P only has bf16 precision anyway).
__device__ __forceinline__ float fast_exp2(float x) {
#if defined(__HIP_DEVICE_COMPILE__) && __has_builtin(__builtin_amdgcn_exp2f)
  return __builtin_amdgcn_exp2f(x);
#else
  return exp2f(x);
#endif
}

__device__ __forceinline__ f32x16 zero16() {
  f32x16 z;
#pragma unroll
  for (int i = 0; i < 16; ++i) z[i] = 0.f;
  return z;
}

// pack two f32 -> one u32 of 2x bf16 (compiler emits v_cvt_pk_bf16_f32)
__device__ __forceinline__ unsigned pkbf(float lo, float hi) {
  bf16x2 t;
  t[0] = (bf16_t)lo;
  t[1] = (bf16_t)hi;
  return __builtin_bit_cast(unsigned, t);
}

// v_permlane32_swap_b32: exchanges vdst-high with vsrc-low.
// After plswap(x, y):  x = {lanes<32: x_old, lanes>=32: y_old[l-32]}  (both lows)
//                      y = {lanes<32: x_old[l+32], lanes>=32: y_old}  (both highs)
__device__ __forceinline__ void plswap(unsigned &x, unsigned &y) {
#if defined(__HIP_DEVICE_COMPILE__)
  i32x2 r = __builtin_amdgcn_permlane32_swap((int)x, (int)y, false, false);
  x = (unsigned)r[0];
  y = (unsigned)r[1];
#endif
}

// From one 32x32 S^T accumulator (rows = 32 kv, cols = 32 q; per-lane reg r
// holds kv_local = (r&3)+8*(r>>2)+4*hi for q = lane&31), produce the two
// K=16 B-operand fragments of P (p0: kv 0..15, p1: kv 16..31), exp2 applied.
__device__ __forceinline__ void build_pa(const f32x16 s, bf16x8 &p0, bf16x8 &p1) {
  unsigned A0 = pkbf(fast_exp2(s[0]),  fast_exp2(s[1]));
  unsigned A1 = pkbf(fast_exp2(s[2]),  fast_exp2(s[3]));
  unsigned B0 = pkbf(fast_exp2(s[4]),  fast_exp2(s[5]));
  unsigned B1 = pkbf(fast_exp2(s[6]),  fast_exp2(s[7]));
  unsigned C0 = pkbf(fast_exp2(s[8]),  fast_exp2(s[9]));
  unsigned C1 = pkbf(fast_exp2(s[10]), fast_exp2(s[11]));
  unsigned D0 = pkbf(fast_exp2(s[12]), fast_exp2(s[13]));
  unsigned D1 = pkbf(fast_exp2(s[14]), fast_exp2(s[15]));
  plswap(A0, B0);  // A0 -> word0 (k = hi*8+{0,1}), B0 -> word2 (k = hi*8+{4,5})
  plswap(A1, B1);  // A1 -> word1,                  B1 -> word3
  plswap(C0, D0);
  plswap(C1, D1);
  u32x4 lo = {A0, A1, B0, B1};
  u32x4 hi = {C0, C1, D0, D1};
  p0 = __builtin_bit_cast(bf16x8, lo);
  p1 = __builtin_bit_cast(bf16x8, hi);
}

// ---------------------------------------------------------------------------
// Kernel 1: MERGED prep — weight transpose (blocks 0..1023) + fp32->bf16
// cast of q,k,v (blocks 1024..25599). One launch instead of two (~10 us of
// launch overhead saved; R7 math shows >=50 us total inter-launch cost).
// Branch is block-uniform; the prep path's __syncthreads is uniform.
// When the workspace is small the host launches only the first 1024 blocks.
// ---------------------------------------------------------------------------
__global__ __launch_bounds__(256) void prep_all(
    const float* __restrict__ q, const float* __restrict__ k,
    const float* __restrict__ v,
    const float* __restrict__ wq, const float* __restrict__ wk,
    const float* __restrict__ wv, const float* __restrict__ wo,
    bf16_t* __restrict__ wtHi, bf16_t* __restrict__ Abf) {
  const int b = blockIdx.x;
  const int t = threadIdx.x;
  __shared__ float T[64][65];

  if (b < 1024) {
    // ---- weight transpose: z = b>>8, n0 = ((b>>4)&15)*64, k0 = (b&15)*64
    const int z = b >> 8;
    const float* W = (z == 0) ? wq : (z == 1) ? wk : (z == 2) ? wv : wo;
    const int k0 = (b & 15) * 64;
    const int n0 = ((b >> 4) & 15) * 64;
#pragma unroll
    for (int rr = 0; rr < 4; ++rr) {
      int row = rr * 16 + (t >> 4);
      int cc = (t & 15) * 4;
      const float4 vv = *(const float4*)&W[(size_t)(k0 + row) * D_ + n0 + cc];
      T[row][cc + 0] = vv.x; T[row][cc + 1] = vv.y;
      T[row][cc + 2] = vv.z; T[row][cc + 3] = vv.w;
    }
    __syncthreads();
    const int n = t >> 2;
    const int kc = (t & 3) * 16;
    bf16x8 h0, h1;
#pragma unroll
    for (int j = 0; j < 16; ++j) {
      float vv = T[kc + j][n];
      if (j < 8) h0[j] = (bf16_t)vv;
      else       h1[j - 8] = (bf16_t)vv;
    }
    size_t ofs = (size_t)z * 1048576 + (size_t)(n0 + n) * D_ + k0 + kc;
    *(bf16x8*)&wtHi[ofs] = h0; *(bf16x8*)&wtHi[ofs + 8] = h1;
  } else {
    // ---- activation cast: bb = b-1024; z = bb>>13, xb = bb&8191
    const int bb = b - 1024;
    const int z = bb >> 13;
    const int xb = bb & 8191;
    const float* src = (z == 0) ? q : (z == 1) ? k : v;
    bf16_t* dst = Abf + (size_t)z * 8388608;
    size_t i = ((size_t)xb * 256 + t) * 4;
    float4 x = *(const float4*)&src[i];
    bf16x4 y;
    y[0] = (bf16_t)x.x; y[1] = (bf16_t)x.y;
    y[2] = (bf16_t)x.z; y[3] = (bf16_t)x.w;
    *(bf16x4*)&dst[i] = y;
  }
}

// ---------------------------------------------------------------------------
// Kernel 2a: QKV projection GEMM, bf16 A, BK=64 (R7-measured config).
// ---------------------------------------------------------------------------
__global__ __launch_bounds__(256) void gemm_qkv_bf16(
    const bf16_t* __restrict__ Abf,
    const float* __restrict__ bq, const float* __restrict__ bk,
    const float* __restrict__ bv,
    const bf16_t* __restrict__ wtHi, bf16_t* __restrict__ outQKV) {
  const int z = blockIdx.z;
  const bf16_t* A   = Abf + (size_t)z * 8388608;
  const float* bias = (z == 0) ? bq : (z == 1) ? bk : bv;
  const bf16_t* WHi = wtHi + (size_t)z * 1048576;
  bf16_t* Out = outQKV + (size_t)z * 8388608;

  const int row0 = blockIdx.x * 128;
  const int col0 = blockIdx.y * 128;
  const int t = threadIdx.x;
  const int w = t >> 6, L = t & 63;
  const int m = L & 15, g = L >> 4;

  __shared__ __align__(16) bf16_t As2[128 * 64];
  __shared__ __align__(16) bf16_t Whi_s[128 * 64];

  f32x4 acc[4][4];
#pragma unroll
  for (int i = 0; i < 4; ++i)
#pragma unroll
    for (int j = 0; j < 4; ++j) acc[i][j] = (f32x4){0.f, 0.f, 0.f, 0.f};

  const int aw0 = (w & 1) * 64;
  const int bw0 = (w >> 1) * 64;

  int srow[4], scol[4];
#pragma unroll
  for (int i = 0; i < 4; ++i) {
    int slot = i * 256 + t;
    srow[i] = slot >> 3;
    scol[i] = (slot & 7) ^ (srow[i] & 7);
  }

  for (int kt = 0; kt < 16; ++kt) {
    const int k0 = kt * 64;
#pragma unroll
    for (int i = 0; i < 4; ++i) {
      gll16(&A[(size_t)(row0 + srow[i]) * D_ + k0 + scol[i] * 8],
            &As2[i * 2048 + w * 512]);
      gll16(&WHi[(size_t)(col0 + srow[i]) * D_ + k0 + scol[i] * 8],
            &Whi_s[i * 2048 + w * 512]);
    }
    __syncthreads();

#pragma unroll
    for (int kh = 0; kh < 2; ++kh) {
      bf16x8 af[4], wh[4];
#pragma unroll
      for (int it = 0; it < 4; ++it) {
        int row = aw0 + it * 16 + m;
        int sl = ((kh * 4 + g) ^ (m & 7)) * 8;
        af[it] = *(const bf16x8*)&As2[row * 64 + sl];
      }
#pragma unroll
      for (int jt = 0; jt < 4; ++jt) {
        int n = bw0 + jt * 16 + m;
        int sl = ((kh * 4 + g) ^ (m & 7)) * 8;
        wh[jt] = *(const bf16x8*)&Whi_s[n * 64 + sl];
      }
#pragma unroll
      for (int it = 0; it < 4; ++it)
#pragma unroll
        for (int jt = 0; jt < 4; ++jt)
          acc[it][jt] = mfma32(af[it], wh[jt], acc[it][jt]);
    }
    __syncthreads();
  }
#pragma unroll
  for (int jt = 0; jt < 4; ++jt) {
    int col = col0 + bw0 + jt * 16 + m;
    float bcol = bias[col];
    int h = col >> 6, d = col & 63;
#pragma unroll
    for (int it = 0; it < 4; ++it) {
      if (z != 2) {
#pragma unroll
        for (int r = 0; r < 4; ++r) {
          int row = row0 + aw0 + it * 16 + g * 4 + r;
          int b = row >> 11, s = row & 2047;
          Out[((size_t)((b * H_ + h) * S_ + s)) * DK_ + d] =
              (bf16_t)(acc[it][jt][r] + bcol);
        }
      } else {
        int row = row0 + aw0 + it * 16 + g * 4;
        int b = row >> 11, s = row & 2047;
        bf16x4 p4;
#pragma unroll
        for (int r = 0; r < 4; ++r) p4[r] = (bf16_t)(acc[it][jt][r] + bcol);
        *(bf16x4*)&Out[((size_t)((b * H_ + h) * DK_ + d)) * S_ + s] = p4;
      }
    }
  }
}

// ---------------------------------------------------------------------------
// Kernel 2b: QKV projection GEMM, fp32 A fallback, single-term W (BK=32,
// unchanged — only used when the workspace is small).
// ---------------------------------------------------------------------------
__global__ __launch_bounds__(256) void gemm_qkv_f32(
    const float* __restrict__ Aq, const float* __restrict__ Ak,
    const float* __restrict__ Av,
    const float* __restrict__ bq, const float* __restrict__ bk,
    const float* __restrict__ bv,
    const bf16_t* __restrict__ wtHi, bf16_t* __restrict__ outQKV) {
  const int z = blockIdx.z;
  const float* A    = (z == 0) ? Aq : (z == 1) ? Ak : Av;
  const float* bias = (z == 0) ? bq : (z == 1) ? bk : bv;
  const bf16_t* WHi = wtHi + (size_t)z * 1048576;
  bf16_t* Out = outQKV + (size_t)z * 8388608;

  const int row0 = blockIdx.x * 128;
  const int col0 = blockIdx.y * 128;
  const int t = threadIdx.x;
  const int w = t >> 6, L = t & 63;
  const int m = L & 15, g = L >> 4;

  __shared__ __align__(16) float  As[128 * 32];
  __shared__ __align__(16) bf16_t Whi_s[128 * 32];

  f32x4 acc[4][4];
#pragma unroll
  for (int i = 0; i < 4; ++i)
#pragma unroll
    for (int j = 0; j < 4; ++j) acc[i][j] = (f32x4){0.f, 0.f, 0.f, 0.f};

  const int aw0 = (w & 1) * 64;
  const int bw0 = (w >> 1) * 64;

  for (int kt = 0; kt < 32; ++kt) {
    const int k0 = kt * 32;
#pragma unroll
    for (int rr = 0; rr < 4; ++rr) {
      int lin16 = rr * 256 + t;
      int row = lin16 >> 3;
      int c = (lin16 & 7) ^ (row & 7);
      gll16(&A[(size_t)(row0 + row) * D_ + k0 + c * 4], &As[rr * 1024 + w * 256]);
    }
#pragma unroll
    for (int rr = 0; rr < 2; ++rr) {
      int lin16 = rr * 256 + t;
      int n = lin16 >> 2;
      int c = (lin16 & 3) ^ ((n >> 1) & 3);
      gll16(&WHi[(size_t)(col0 + n) * D_ + k0 + c * 8], &Whi_s[rr * 2048 + w * 512]);
    }
    __syncthreads();

    bf16x8 af[4], wh[4];
#pragma unroll
    for (int it = 0; it < 4; ++it) {
      int row = aw0 + it * 16 + m;
      const f32x4* p = (const f32x4*)&As[row * 32];
      f32x4 x0 = p[(2 * g) ^ (m & 7)];
      f32x4 x1 = p[(2 * g + 1) ^ (m & 7)];
      bf16x8 a;
      a[0] = (bf16_t)x0.x; a[1] = (bf16_t)x0.y; a[2] = (bf16_t)x0.z; a[3] = (bf16_t)x0.w;
      a[4] = (bf16_t)x1.x; a[5] = (bf16_t)x1.y; a[6] = (bf16_t)x1.z; a[7] = (bf16_t)x1.w;
      af[it] = a;
    }
#pragma unroll
    for (int jt = 0; jt < 4; ++jt) {
      int n = bw0 + jt * 16 + m;
      int sl = (g ^ ((m >> 1) & 3)) * 8;
      wh[jt] = *(const bf16x8*)&Whi_s[n * 32 + sl];
    }
#pragma unroll
    for (int it = 0; it < 4; ++it)
#pragma unroll
      for (int jt = 0; jt < 4; ++jt)
        acc[it][jt] = mfma32(af[it], wh[jt], acc[it][jt]);
    __syncthreads();
  }
#pragma unroll
  for (int jt = 0; jt < 4; ++jt) {
    int col = col0 + bw0 + jt * 16 + m;
    float bcol = bias[col];
    int h = col >> 6, d = col & 63;
#pragma unroll
    for (int it = 0; it < 4; ++it) {
      if (z != 2) {
#pragma unroll
        for (int r = 0; r < 4; ++r) {
          int row = row0 + aw0 + it * 16 + g * 4 + r;
          int b = row >> 11, s = row & 2047;
          Out[((size_t)((b * H_ + h) * S_ + s)) * DK_ + d] =
              (bf16_t)(acc[it][jt][r] + bcol);
        }
      } else {
        int row = row0 + aw0 + it * 16 + g * 4;
        int b = row >> 11, s = row & 2047;
        bf16x4 p4;
#pragma unroll
        for (int r = 0; r < 4; ++r) p4[r] = (bf16_t)(acc[it][jt][r] + bcol);
        *(bf16x4*)&Out[((size_t)((b * H_ + h) * DK_ + d)) * S_ + s] = p4;
      }
    }
  }
}

// ---------------------------------------------------------------------------
// Kernel 3: flash attention on 32x32x16 MFMA (T12 structure) — measured-best
// config (86.0 us R7 / 83.1 us R1 bench): 4-wave/256-thread blocks,
// single-buffered 16 KB LDS, no dbuf, no XCD swizzle. Three scheduling
// variants (dbuf+swizzle, T15 deferred-PV, 2-wave blocks) all measured
// slower; this is the empirical optimum of the family.
// ---------------------------------------------------------------------------
__global__ __launch_bounds__(256, 2) void attn(
    const bf16_t* __restrict__ Qh, const bf16_t* __restrict__ Kh,
    const bf16_t* __restrict__ VhT, bf16_t* __restrict__ Ohi) {
  const int bh = blockIdx.y;
  const int q0 = blockIdx.x * 128;
  const int t = threadIdx.x, w = t >> 6;
  const int lane = t & 63;
  const int lo5 = lane & 31, hi = lane >> 5;

  __shared__ __align__(16) bf16_t Ks[64 * 64];  // [kv][d], xor-swizzled chunks
  __shared__ __align__(16) bf16_t Vt[64 * 64];  // [d][kv], xor-swizzled chunks

  const size_t qbase = (size_t)bh * S_ * DK_;
  const size_t vbase = (size_t)bh * DK_ * S_;

  const int qrow = q0 + w * 32 + lo5;
  bf16x8 qf[4];
#pragma unroll
  for (int ks = 0; ks < 4; ++ks) {
    bf16x8 v = *(const bf16x8*)&Qh[qbase + (size_t)qrow * DK_ + ks * 16 + hi * 8];
#pragma unroll
    for (int j = 0; j < 8; ++j) v[j] = (bf16_t)(0.18033688f * (float)v[j]);
    qf[ks] = v;
  }

  bf16x8 ones;
#pragma unroll
  for (int j = 0; j < 8; ++j) ones[j] = (bf16_t)1.f;

  int offs[4];
#pragma unroll
  for (int ks = 0; ks < 4; ++ks)
    offs[ks] = lo5 * 64 + (((ks * 2 + hi) ^ (lo5 & 7)) * 8);

  f32x16 oacc0 = zero16(), oacc1 = zero16(), lacc = zero16();

  for (int kv0 = 0; kv0 < S_; kv0 += 64) {
#pragma unroll
    for (int rr = 0; rr < 2; ++rr) {
      int lin16 = rr * 256 + t;
      int rrow = lin16 >> 3;
      int c = (lin16 & 7) ^ (rrow & 7);
      gll16(&Kh[qbase + (size_t)(kv0 + rrow) * DK_ + c * 8], &Ks[rr * 2048 + w * 512]);
      gll16(&VhT[vbase + (size_t)rrow * S_ + kv0 + c * 8], &Vt[rr * 2048 + w * 512]);
    }
    __syncthreads();

    f32x16 sc0 = zero16(), sc1 = zero16();
#pragma unroll
    for (int ks = 0; ks < 4; ++ks) {
      bf16x8 k0 = *(const bf16x8*)&Ks[offs[ks]];
      bf16x8 k1 = *(const bf16x8*)&Ks[offs[ks] + 2048];
      sc0 = mfma32x32(k0, qf[ks], sc0);
      sc1 = mfma32x32(k1, qf[ks], sc1);
    }

    bf16x8 pa0, pa1, pa2, pa3;
    build_pa(sc0, pa0, pa1);
    build_pa(sc1, pa2, pa3);

#pragma unroll
    for (int ks = 0; ks < 4; ++ks) {
      bf16x8 pb = (ks == 0) ? pa0 : (ks == 1) ? pa1 : (ks == 2) ? pa2 : pa3;
      lacc = mfma32x32(ones, pb, lacc);
      bf16x8 v0 = *(const bf16x8*)&Vt[offs[ks]];
      bf16x8 v1 = *(const bf16x8*)&Vt[offs[ks] + 2048];
      oacc0 = mfma32x32(v0, pb, oacc0);
      oacc1 = mfma32x32(v1, pb, oacc1);
    }
    __syncthreads();
  }

  const int b = bh >> 4, h = bh & 15;
  const float inv = 1.f / lacc[0];
  const size_t rowofs = ((size_t)(b * S_ + qrow)) * D_ + h * DK_;
#pragma unroll
  for (int rg = 0; rg < 4; ++rg) {
    bf16x4 o0, o1;
#pragma unroll
    for (int j = 0; j < 4; ++j) {
      o0[j] = (bf16_t)(oacc0[rg * 4 + j] * inv);
      o1[j] = (bf16_t)(oacc1[rg * 4 + j] * inv);
    }
    *(bf16x4*)&Ohi[rowofs + rg * 8 + hi * 4] = o0;
    *(bf16x4*)&Ohi[rowofs + 32 + rg * 8 + hi * 4] = o1;
  }
}

// ---------------------------------------------------------------------------
// Kernel 4: output projection, BK=64, now DOUBLE-BUFFERED gll16 prefetch.
// Rationale: grid is only 512 blocks = 2 blocks/CU (8 waves) — too few for
// TLP to cover the gll16->barrier drain (unlike the 1536-block QKV GEMM).
// STAGE(kt+1 -> buf^1) issues before the 32-MFMA compute on buf; one
// barrier/iter drains it after the latency has been hidden. LDS 64 KB
// changes nothing here (grid caps residency at 2 blocks/CU either way).
// ---------------------------------------------------------------------------
__global__ __launch_bounds__(256) void gemm_out(
    const bf16_t* __restrict__ Ahi, const bf16_t* __restrict__ wtHi,
    const float* __restrict__ bias, float* __restrict__ Out) {
  const bf16_t* WHi = wtHi + (size_t)3 * 1048576;
  const int row0 = blockIdx.x * 128;
  const int col0 = blockIdx.y * 128;
  const int t = threadIdx.x;
  const int w = t >> 6, L = t & 63;
  const int m = L & 15, g = L >> 4;

  __shared__ __align__(16) bf16_t Ahi_s[2][128 * 64];
  __shared__ __align__(16) bf16_t Whi_s[2][128 * 64];

  f32x4 acc[4][4];
#pragma unroll
  for (int i = 0; i < 4; ++i)
#pragma unroll
    for (int j = 0; j < 4; ++j) acc[i][j] = (f32x4){0.f, 0.f, 0.f, 0.f};

  const int aw0 = (w & 1) * 64;
  const int bw0 = (w >> 1) * 64;

  int srow[4], scol[4];
#pragma unroll
  for (int i = 0; i < 4; ++i) {
    int slot = i * 256 + t;
    srow[i] = slot >> 3;
    scol[i] = (slot & 7) ^ (srow[i] & 7);
  }

#define OSTAGE(buf, k0)                                                        \
  do {                                                                         \
    _Pragma("unroll")                                                          \
    for (int i = 0; i < 4; ++i) {                                              \
      gll16(&Ahi[(size_t)(row0 + srow[i]) * D_ + (k0) + scol[i] * 8],          \
            &Ahi_s[buf][i * 2048 + w * 512]);                                  \
      gll16(&WHi[(size_t)(col0 + srow[i]) * D_ + (k0) + scol[i] * 8],          \
            &Whi_s[buf][i * 2048 + w * 512]);                                  \
    }                                                                          \
  } while (0)

  OSTAGE(0, 0);
  __syncthreads();

  for (int kt = 0; kt < 16; ++kt) {
    const int c = kt & 1;
    if (kt < 15) OSTAGE(c ^ 1, (kt + 1) * 64);  // prefetch under compute

    const bf16_t* as_b = &Ahi_s[c][0];
    const bf16_t* ws_b = &Whi_s[c][0];
#pragma unroll
    for (int kh = 0; kh < 2; ++kh) {
      bf16x8 ah[4], wh[4];
#pragma unroll
      for (int it = 0; it < 4; ++it) {
        int row = aw0 + it * 16 + m;
        int sl = ((kh * 4 + g) ^ (m & 7)) * 8;
        ah[it] = *(const bf16x8*)&as_b[row * 64 + sl];
      }
#pragma unroll
      for (int jt = 0; jt < 4; ++jt) {
        int n = bw0 + jt * 16 + m;
        int sl = ((kh * 4 + g) ^ (m & 7)) * 8;
        wh[jt] = *(const bf16x8*)&ws_b[n * 64 + sl];
      }
#pragma unroll
      for (int it = 0; it < 4; ++it)
#pragma unroll
        for (int jt = 0; jt < 4; ++jt)
          acc[it][jt] = mfma32(ah[it], wh[jt], acc[it][jt]);
    }
    __syncthreads();  // drains prefetch (hidden) + protects buf reuse
  }
#undef OSTAGE

#pragma unroll
  for (int jt = 0; jt < 4; ++jt) {
    int col = col0 + bw0 + jt * 16 + m;
    float bcol = bias[col];
#pragma unroll
    for (int it = 0; it < 4; ++it)
#pragma unroll
      for (int r = 0; r < 4; ++r) {
        int row = row0 + aw0 + it * 16 + g * 4 + r;
        Out[(size_t)row * D_ + col] = acc[it][jt][r] + bcol;
      }
  }
}

// ---------------------------------------------------------------------------
extern "C" void kernel_launch(void* const* d_in, const int* in_sizes, int n_in,
                              void* d_out, int out_size, void* d_ws, size_t ws_size,
                              hipStream_t stream) {
  const float* q  = (const float*)d_in[0];
  const float* k  = (const float*)d_in[1];
  const float* v  = (const float*)d_in[2];
  const float* wq = (const float*)d_in[3];
  const float* bq = (const float*)d_in[4];
  const float* wk = (const float*)d_in[5];
  const float* bk = (const float*)d_in[6];
  const float* wv = (const float*)d_in[7];
  const float* bv = (const float*)d_in[8];
  const float* wo = (const float*)d_in[9];
  const float* bo = (const float*)d_in[10];
  float* out = (float*)d_out;

  char* ws = (char*)d_ws;
  bf16_t* wtHi = (bf16_t*)(ws);                      // 8 MB
  bf16_t* QKVh = (bf16_t*)(ws + (8ull << 20));       // 48 MB (Qh, Kh, VhT)
  bf16_t* Ohi  = (bf16_t*)(ws + (56ull << 20));      // 16 MB
  bf16_t* Abf  = (bf16_t*)(ws + (56ull << 20));      // 48 MB (overlaps Ohi)

  const bool big = ws_size >= (104ull << 20);

  if (big) {
    // merged weight-transpose + activation-cast: one launch
    hipLaunchKernelGGL(prep_all, dim3(25600), dim3(256), 0, stream,
                       q, k, v, wq, wk, wv, wo, wtHi, Abf);
    hipLaunchKernelGGL(gemm_qkv_bf16, dim3(64, 8, 3), dim3(256), 0, stream,
                       Abf, bq, bk, bv, wtHi, QKVh);
  } else {
    hipLaunchKernelGGL(prep_all, dim3(1024), dim3(256), 0, stream,
                       q, k, v, wq, wk, wv, wo, wtHi, (bf16_t*)wtHi /*unused*/);
    hipLaunchKernelGGL(gemm_qkv_f32, dim3(64, 8, 3), dim3(256), 0, stream,
                       q, k, v, bq, bk, bv, wtHi, QKVh);
  }
  hipLaunchKernelGGL(attn, dim3(16, 64), dim3(256), 0, stream,
                     QKVh, QKVh + 8388608, QKVh + 16777216, Ohi);
  hipLaunchKernelGGL(gemm_out, dim3(64, 8), dim3(256), 0, stream,
                     Ohi, wtHi, bo, out);
}

// Round 11
// 335.972 us; speedup vs baseline: 1.1127x; 1.0110x over previous
//
#include <hip/hip_runtime.h>
#include <hip/hip_bf16.h>

#define B_   4
#define S_   2048
#define D_   1024
#define H_   16
#define DK_  64
#define NTOK 8192

typedef __bf16 bf16_t;
typedef __bf16 bf16x8 __attribute__((ext_vector_type(8)));
typedef __bf16 bf16x4 __attribute__((ext_vector_type(4)));
typedef __bf16 bf16x2 __attribute__((ext_vector_type(2)));
typedef float  f32x4  __attribute__((ext_vector_type(4)));
typedef float  f32x16 __attribute__((ext_vector_type(16)));
typedef unsigned u32x4 __attribute__((ext_vector_type(4)));
typedef int    i32x2  __attribute__((ext_vector_type(2)));

__device__ __forceinline__ void gll16(const void* g, void* l) {
  __builtin_amdgcn_global_load_lds(
      (const __attribute__((address_space(1))) void*)g,
      (__attribute__((address_space(3))) void*)l,
      16, 0, 0);
}

__device__ __forceinline__ f32x4 mfma32(bf16x8 a, bf16x8 b, f32x4 c) {
  return __builtin_amdgcn_mfma_f32_16x16x32_bf16(a, b, c, 0, 0, 0);
}

__device__ __forceinline__ f32x16 mfma32x32(bf16x8 a, bf16x8 b, f32x16 c) {
#if defined(__HIP_DEVICE_COMPILE__)
  return __builtin_amdgcn_mfma_f32_32x32x16_bf16(a, b, c, 0, 0, 0);
#else
  (void)a; (void)b;
  return c;
#endif
}

// Single-instruction v_exp_f32 (exp2f without -ffast-math takes the OCML
// precise path we don't need — P only has bf16 precision anyway).
__device__ __forceinline__ float fast_exp2(float x) {
#if defined(__HIP_DEVICE_COMPILE__) && __has_builtin(__builtin_amdgcn_exp2f)
  return __builtin_amdgcn_exp2f(x);
#else
  return exp2f(x);
#endif
}

__device__ __forceinline__ f32x16 zero16() {
  f32x16 z;
#pragma unroll
  for (int i = 0; i < 16; ++i) z[i] = 0.f;
  return z;
}

// pack two f32 -> one u32 of 2x bf16 (compiler emits v_cvt_pk_bf16_f32)
__device__ __forceinline__ unsigned pkbf(float lo, float hi) {
  bf16x2 t;
  t[0] = (bf16_t)lo;
  t[1] = (bf16_t)hi;
  return __builtin_bit_cast(unsigned, t);
}

// v_permlane32_swap_b32: exchanges vdst-high with vsrc-low.
// After plswap(x, y):  x = {lanes<32: x_old, lanes>=32: y_old[l-32]}  (both lows)
//                      y = {lanes<32: x_old[l+32], lanes>=32: y_old}  (both highs)
__device__ __forceinline__ void plswap(unsigned &x, unsigned &y) {
#if defined(__HIP_DEVICE_COMPILE__)
  i32x2 r = __builtin_amdgcn_permlane32_swap((int)x, (int)y, false, false);
  x = (unsigned)r[0];
  y = (unsigned)r[1];
#endif
}

// From one 32x32 S^T accumulator (rows = 32 kv, cols = 32 q; per-lane reg r
// holds kv_local = (r&3)+8*(r>>2)+4*hi for q = lane&31), produce the two
// K=16 B-operand fragments of P (p0: kv 0..15, p1: kv 16..31), exp2 applied.
__device__ __forceinline__ void build_pa(const f32x16 s, bf16x8 &p0, bf16x8 &p1) {
  unsigned A0 = pkbf(fast_exp2(s[0]),  fast_exp2(s[1]));
  unsigned A1 = pkbf(fast_exp2(s[2]),  fast_exp2(s[3]));
  unsigned B0 = pkbf(fast_exp2(s[4]),  fast_exp2(s[5]));
  unsigned B1 = pkbf(fast_exp2(s[6]),  fast_exp2(s[7]));
  unsigned C0 = pkbf(fast_exp2(s[8]),  fast_exp2(s[9]));
  unsigned C1 = pkbf(fast_exp2(s[10]), fast_exp2(s[11]));
  unsigned D0 = pkbf(fast_exp2(s[12]), fast_exp2(s[13]));
  unsigned D1 = pkbf(fast_exp2(s[14]), fast_exp2(s[15]));
  plswap(A0, B0);  // A0 -> word0 (k = hi*8+{0,1}), B0 -> word2 (k = hi*8+{4,5})
  plswap(A1, B1);  // A1 -> word1,                  B1 -> word3
  plswap(C0, D0);
  plswap(C1, D1);
  u32x4 lo = {A0, A1, B0, B1};
  u32x4 hi = {C0, C1, D0, D1};
  p0 = __builtin_bit_cast(bf16x8, lo);
  p1 = __builtin_bit_cast(bf16x8, hi);
}

// ---------------------------------------------------------------------------
// Kernel 1: MERGED prep — weight transpose (blocks 0..1023) + fp32->bf16
// cast of q,k,v (blocks 1024..25599). One launch. Branch is block-uniform.
// ---------------------------------------------------------------------------
__global__ __launch_bounds__(256) void prep_all(
    const float* __restrict__ q, const float* __restrict__ k,
    const float* __restrict__ v,
    const float* __restrict__ wq, const float* __restrict__ wk,
    const float* __restrict__ wv, const float* __restrict__ wo,
    bf16_t* __restrict__ wtHi, bf16_t* __restrict__ Abf) {
  const int b = blockIdx.x;
  const int t = threadIdx.x;
  __shared__ float T[64][65];

  if (b < 1024) {
    const int z = b >> 8;
    const float* W = (z == 0) ? wq : (z == 1) ? wk : (z == 2) ? wv : wo;
    const int k0 = (b & 15) * 64;
    const int n0 = ((b >> 4) & 15) * 64;
#pragma unroll
    for (int rr = 0; rr < 4; ++rr) {
      int row = rr * 16 + (t >> 4);
      int cc = (t & 15) * 4;
      const float4 vv = *(const float4*)&W[(size_t)(k0 + row) * D_ + n0 + cc];
      T[row][cc + 0] = vv.x; T[row][cc + 1] = vv.y;
      T[row][cc + 2] = vv.z; T[row][cc + 3] = vv.w;
    }
    __syncthreads();
    const int n = t >> 2;
    const int kc = (t & 3) * 16;
    bf16x8 h0, h1;
#pragma unroll
    for (int j = 0; j < 16; ++j) {
      float vv = T[kc + j][n];
      if (j < 8) h0[j] = (bf16_t)vv;
      else       h1[j - 8] = (bf16_t)vv;
    }
    size_t ofs = (size_t)z * 1048576 + (size_t)(n0 + n) * D_ + k0 + kc;
    *(bf16x8*)&wtHi[ofs] = h0; *(bf16x8*)&wtHi[ofs + 8] = h1;
  } else {
    const int bb = b - 1024;
    const int z = bb >> 13;
    const int xb = bb & 8191;
    const float* src = (z == 0) ? q : (z == 1) ? k : v;
    bf16_t* dst = Abf + (size_t)z * 8388608;
    size_t i = ((size_t)xb * 256 + t) * 4;
    float4 x = *(const float4*)&src[i];
    bf16x4 y;
    y[0] = (bf16_t)x.x; y[1] = (bf16_t)x.y;
    y[2] = (bf16_t)x.z; y[3] = (bf16_t)x.w;
    *(bf16x4*)&dst[i] = y;
  }
}

// ---------------------------------------------------------------------------
// Kernel 2a: QKV projection GEMM, bf16 A, BK=32, COUNTED-VMCNT double buffer
// (T3/T4-minimal recipe). Key insight from R10's null dbuf: __syncthreads
// drains vmcnt(0), serializing any prefetch. Here: STAGE(next) -> inline-asm
// s_waitcnt vmcnt(4) (old buffer's 4 loads done, new 4 stay in flight) ->
// raw s_barrier -> 16 MFMA -> raw s_barrier. LDS 2x16 KB = 32 KB keeps
// occupancy ~5 blocks/CU (avoids R9's 64 KB occupancy trap).
// XCD-chunked 1-D id swizzle: per super-round, each XCD gets 64 consecutive
// blocks = 8 row-tiles x 8 cols => 2 MB A-panel + 2 MB W fits its 4 MB L2.
// ---------------------------------------------------------------------------
__global__ __launch_bounds__(256) void gemm_qkv_bf16(
    const bf16_t* __restrict__ Abf,
    const float* __restrict__ bq, const float* __restrict__ bk,
    const float* __restrict__ bv,
    const bf16_t* __restrict__ wtHi, bf16_t* __restrict__ outQKV) {
  // dispatch id d -> swz: super-round s = d>>9 (one z-slab each), XCD x = d&7
  // gets within-round chunk [x*64, x*64+64) = rows 8x..8x+7, all 8 col-tiles.
  const int d = blockIdx.x;
  const int swz = (d >> 9) * 512 + (d & 7) * 64 + ((d & 511) >> 3);
  const int z = swz >> 9;
  const int rblk = swz & 511;
  const int row0 = (rblk >> 3) * 128;
  const int col0 = (rblk & 7) * 128;

  const bf16_t* A   = Abf + (size_t)z * 8388608;
  const float* bias = (z == 0) ? bq : (z == 1) ? bk : bv;
  const bf16_t* WHi = wtHi + (size_t)z * 1048576;
  bf16_t* Out = outQKV + (size_t)z * 8388608;

  const int t = threadIdx.x;
  const int w = t >> 6, L = t & 63;
  const int m = L & 15, g = L >> 4;

  __shared__ __align__(16) bf16_t As2[2][128 * 32];
  __shared__ __align__(16) bf16_t Whi_s[2][128 * 32];

  f32x4 acc[4][4];
#pragma unroll
  for (int i = 0; i < 4; ++i)
#pragma unroll
    for (int j = 0; j < 4; ++j) acc[i][j] = (f32x4){0.f, 0.f, 0.f, 0.f};

  const int aw0 = (w & 1) * 64;
  const int bw0 = (w >> 1) * 64;

  // R1-proven BK=32 staging addresses
  int n_[2], c_[2];
#pragma unroll
  for (int rr = 0; rr < 2; ++rr) {
    int lin16 = rr * 256 + t;
    n_[rr] = lin16 >> 2;
    c_[rr] = (lin16 & 3) ^ ((n_[rr] >> 1) & 3);
  }

#define QSTAGE(buf, k0)                                                        \
  do {                                                                         \
    _Pragma("unroll")                                                          \
    for (int rr = 0; rr < 2; ++rr) {                                           \
      gll16(&A[(size_t)(row0 + n_[rr]) * D_ + (k0) + c_[rr] * 8],              \
            &As2[buf][rr * 2048 + w * 512]);                                   \
      gll16(&WHi[(size_t)(col0 + n_[rr]) * D_ + (k0) + c_[rr] * 8],            \
            &Whi_s[buf][rr * 2048 + w * 512]);                                 \
    }                                                                          \
  } while (0)

  QSTAGE(0, 0);  // 4 loads in flight

  for (int kt = 0; kt < 32; ++kt) {
    const int c = kt & 1;
    if (kt < 31) {
      QSTAGE(c ^ 1, (kt + 1) * 32);  // 8 in flight (4 old + 4 new)
      asm volatile("s_waitcnt vmcnt(4)" ::: "memory");  // old 4 done
    } else {
      asm volatile("s_waitcnt vmcnt(0)" ::: "memory");
    }
    __builtin_amdgcn_s_barrier();  // all waves' current buffer complete

    const bf16_t* as_b = &As2[c][0];
    const bf16_t* ws_b = &Whi_s[c][0];
    bf16x8 af[4], wh[4];
#pragma unroll
    for (int it = 0; it < 4; ++it) {
      int row = aw0 + it * 16 + m;
      int sl = (g ^ ((m >> 1) & 3)) * 8;
      af[it] = *(const bf16x8*)&as_b[row * 32 + sl];
    }
#pragma unroll
    for (int jt = 0; jt < 4; ++jt) {
      int n = bw0 + jt * 16 + m;
      int sl = (g ^ ((m >> 1) & 3)) * 8;
      wh[jt] = *(const bf16x8*)&ws_b[n * 32 + sl];
    }
#pragma unroll
    for (int it = 0; it < 4; ++it)
#pragma unroll
      for (int jt = 0; jt < 4; ++jt)
        acc[it][jt] = mfma32(af[it], wh[jt], acc[it][jt]);

    __builtin_amdgcn_s_barrier();  // all waves done reading buf c
  }
#undef QSTAGE

#pragma unroll
  for (int jt = 0; jt < 4; ++jt) {
    int col = col0 + bw0 + jt * 16 + m;
    float bcol = bias[col];
    int h = col >> 6, dd = col & 63;
#pragma unroll
    for (int it = 0; it < 4; ++it) {
      if (z != 2) {
#pragma unroll
        for (int r = 0; r < 4; ++r) {
          int row = row0 + aw0 + it * 16 + g * 4 + r;
          int b = row >> 11, s = row & 2047;
          Out[((size_t)((b * H_ + h) * S_ + s)) * DK_ + dd] =
              (bf16_t)(acc[it][jt][r] + bcol);
        }
      } else {
        int row = row0 + aw0 + it * 16 + g * 4;
        int b = row >> 11, s = row & 2047;
        bf16x4 p4;
#pragma unroll
        for (int r = 0; r < 4; ++r) p4[r] = (bf16_t)(acc[it][jt][r] + bcol);
        *(bf16x4*)&Out[((size_t)((b * H_ + h) * DK_ + dd)) * S_ + s] = p4;
      }
    }
  }
}

// ---------------------------------------------------------------------------
// Kernel 2b: QKV projection GEMM, fp32 A fallback (BK=32, unchanged — only
// used when the workspace is small).
// ---------------------------------------------------------------------------
__global__ __launch_bounds__(256) void gemm_qkv_f32(
    const float* __restrict__ Aq, const float* __restrict__ Ak,
    const float* __restrict__ Av,
    const float* __restrict__ bq, const float* __restrict__ bk,
    const float* __restrict__ bv,
    const bf16_t* __restrict__ wtHi, bf16_t* __restrict__ outQKV) {
  const int z = blockIdx.z;
  const float* A    = (z == 0) ? Aq : (z == 1) ? Ak : Av;
  const float* bias = (z == 0) ? bq : (z == 1) ? bk : bv;
  const bf16_t* WHi = wtHi + (size_t)z * 1048576;
  bf16_t* Out = outQKV + (size_t)z * 8388608;

  const int row0 = blockIdx.x * 128;
  const int col0 = blockIdx.y * 128;
  const int t = threadIdx.x;
  const int w = t >> 6, L = t & 63;
  const int m = L & 15, g = L >> 4;

  __shared__ __align__(16) float  As[128 * 32];
  __shared__ __align__(16) bf16_t Whi_s[128 * 32];

  f32x4 acc[4][4];
#pragma unroll
  for (int i = 0; i < 4; ++i)
#pragma unroll
    for (int j = 0; j < 4; ++j) acc[i][j] = (f32x4){0.f, 0.f, 0.f, 0.f};

  const int aw0 = (w & 1) * 64;
  const int bw0 = (w >> 1) * 64;

  for (int kt = 0; kt < 32; ++kt) {
    const int k0 = kt * 32;
#pragma unroll
    for (int rr = 0; rr < 4; ++rr) {
      int lin16 = rr * 256 + t;
      int row = lin16 >> 3;
      int c = (lin16 & 7) ^ (row & 7);
      gll16(&A[(size_t)(row0 + row) * D_ + k0 + c * 4], &As[rr * 1024 + w * 256]);
    }
#pragma unroll
    for (int rr = 0; rr < 2; ++rr) {
      int lin16 = rr * 256 + t;
      int n = lin16 >> 2;
      int c = (lin16 & 3) ^ ((n >> 1) & 3);
      gll16(&WHi[(size_t)(col0 + n) * D_ + k0 + c * 8], &Whi_s[rr * 2048 + w * 512]);
    }
    __syncthreads();

    bf16x8 af[4], wh[4];
#pragma unroll
    for (int it = 0; it < 4; ++it) {
      int row = aw0 + it * 16 + m;
      const f32x4* p = (const f32x4*)&As[row * 32];
      f32x4 x0 = p[(2 * g) ^ (m & 7)];
      f32x4 x1 = p[(2 * g + 1) ^ (m & 7)];
      bf16x8 a;
      a[0] = (bf16_t)x0.x; a[1] = (bf16_t)x0.y; a[2] = (bf16_t)x0.z; a[3] = (bf16_t)x0.w;
      a[4] = (bf16_t)x1.x; a[5] = (bf16_t)x1.y; a[6] = (bf16_t)x1.z; a[7] = (bf16_t)x1.w;
      af[it] = a;
    }
#pragma unroll
    for (int jt = 0; jt < 4; ++jt) {
      int n = bw0 + jt * 16 + m;
      int sl = (g ^ ((m >> 1) & 3)) * 8;
      wh[jt] = *(const bf16x8*)&Whi_s[n * 32 + sl];
    }
#pragma unroll
    for (int it = 0; it < 4; ++it)
#pragma unroll
      for (int jt = 0; jt < 4; ++jt)
        acc[it][jt] = mfma32(af[it], wh[jt], acc[it][jt]);
    __syncthreads();
  }
#pragma unroll
  for (int jt = 0; jt < 4; ++jt) {
    int col = col0 + bw0 + jt * 16 + m;
    float bcol = bias[col];
    int h = col >> 6, dd = col & 63;
#pragma unroll
    for (int it = 0; it < 4; ++it) {
      if (z != 2) {
#pragma unroll
        for (int r = 0; r < 4; ++r) {
          int row = row0 + aw0 + it * 16 + g * 4 + r;
          int b = row >> 11, s = row & 2047;
          Out[((size_t)((b * H_ + h) * S_ + s)) * DK_ + dd] =
              (bf16_t)(acc[it][jt][r] + bcol);
        }
      } else {
        int row = row0 + aw0 + it * 16 + g * 4;
        int b = row >> 11, s = row & 2047;
        bf16x4 p4;
#pragma unroll
        for (int r = 0; r < 4; ++r) p4[r] = (bf16_t)(acc[it][jt][r] + bcol);
        *(bf16x4*)&Out[((size_t)((b * H_ + h) * DK_ + dd)) * S_ + s] = p4;
      }
    }
  }
}

// ---------------------------------------------------------------------------
// Kernel 3: flash attention on 32x32x16 MFMA (T12 structure) — measured-best
// config (83.8 us R10): 4-wave/256-thread blocks, single-buffered 16 KB LDS,
// no dbuf, no XCD swizzle. Unchanged.
// ---------------------------------------------------------------------------
__global__ __launch_bounds__(256, 2) void attn(
    const bf16_t* __restrict__ Qh, const bf16_t* __restrict__ Kh,
    const bf16_t* __restrict__ VhT, bf16_t* __restrict__ Ohi) {
  const int bh = blockIdx.y;
  const int q0 = blockIdx.x * 128;
  const int t = threadIdx.x, w = t >> 6;
  const int lane = t & 63;
  const int lo5 = lane & 31, hi = lane >> 5;

  __shared__ __align__(16) bf16_t Ks[64 * 64];  // [kv][d], xor-swizzled chunks
  __shared__ __align__(16) bf16_t Vt[64 * 64];  // [d][kv], xor-swizzled chunks

  const size_t qbase = (size_t)bh * S_ * DK_;
  const size_t vbase = (size_t)bh * DK_ * S_;

  const int qrow = q0 + w * 32 + lo5;
  bf16x8 qf[4];
#pragma unroll
  for (int ks = 0; ks < 4; ++ks) {
    bf16x8 v = *(const bf16x8*)&Qh[qbase + (size_t)qrow * DK_ + ks * 16 + hi * 8];
#pragma unroll
    for (int j = 0; j < 8; ++j) v[j] = (bf16_t)(0.18033688f * (float)v[j]);
    qf[ks] = v;
  }

  bf16x8 ones;
#pragma unroll
  for (int j = 0; j < 8; ++j) ones[j] = (bf16_t)1.f;

  int offs[4];
#pragma unroll
  for (int ks = 0; ks < 4; ++ks)
    offs[ks] = lo5 * 64 + (((ks * 2 + hi) ^ (lo5 & 7)) * 8);

  f32x16 oacc0 = zero16(), oacc1 = zero16(), lacc = zero16();

  for (int kv0 = 0; kv0 < S_; kv0 += 64) {
#pragma unroll
    for (int rr = 0; rr < 2; ++rr) {
      int lin16 = rr * 256 + t;
      int rrow = lin16 >> 3;
      int c = (lin16 & 7) ^ (rrow & 7);
      gll16(&Kh[qbase + (size_t)(kv0 + rrow) * DK_ + c * 8], &Ks[rr * 2048 + w * 512]);
      gll16(&VhT[vbase + (size_t)rrow * S_ + kv0 + c * 8], &Vt[rr * 2048 + w * 512]);
    }
    __syncthreads();

    f32x16 sc0 = zero16(), sc1 = zero16();
#pragma unroll
    for (int ks = 0; ks < 4; ++ks) {
      bf16x8 k0 = *(const bf16x8*)&Ks[offs[ks]];
      bf16x8 k1 = *(const bf16x8*)&Ks[offs[ks] + 2048];
      sc0 = mfma32x32(k0, qf[ks], sc0);
      sc1 = mfma32x32(k1, qf[ks], sc1);
    }

    bf16x8 pa0, pa1, pa2, pa3;
    build_pa(sc0, pa0, pa1);
    build_pa(sc1, pa2, pa3);

#pragma unroll
    for (int ks = 0; ks < 4; ++ks) {
      bf16x8 pb = (ks == 0) ? pa0 : (ks == 1) ? pa1 : (ks == 2) ? pa2 : pa3;
      lacc = mfma32x32(ones, pb, lacc);
      bf16x8 v0 = *(const bf16x8*)&Vt[offs[ks]];
      bf16x8 v1 = *(const bf16x8*)&Vt[offs[ks] + 2048];
      oacc0 = mfma32x32(v0, pb, oacc0);
      oacc1 = mfma32x32(v1, pb, oacc1);
    }
    __syncthreads();
  }

  const int b = bh >> 4, h = bh & 15;
  const float inv = 1.f / lacc[0];
  const size_t rowofs = ((size_t)(b * S_ + qrow)) * D_ + h * DK_;
#pragma unroll
  for (int rg = 0; rg < 4; ++rg) {
    bf16x4 o0, o1;
#pragma unroll
    for (int j = 0; j < 4; ++j) {
      o0[j] = (bf16_t)(oacc0[rg * 4 + j] * inv);
      o1[j] = (bf16_t)(oacc1[rg * 4 + j] * inv);
    }
    *(bf16x4*)&Ohi[rowofs + rg * 8 + hi * 4] = o0;
    *(bf16x4*)&Ohi[rowofs + 32 + rg * 8 + hi * 4] = o1;
  }
}

// ---------------------------------------------------------------------------
// Kernel 4: output projection, BK=64, COUNTED-VMCNT double buffer + XCD
// swizzle. R10's plain-__syncthreads dbuf was null because the barrier
// drains vmcnt(0); here the prefetch's 8 loads stay in flight across the
// barrier (s_waitcnt vmcnt(8) + raw s_barrier).
// ---------------------------------------------------------------------------
__global__ __launch_bounds__(256) void gemm_out(
    const bf16_t* __restrict__ Ahi, const bf16_t* __restrict__ wtHi,
    const float* __restrict__ bias, float* __restrict__ Out) {
  const bf16_t* WHi = wtHi + (size_t)3 * 1048576;
  // XCD chunk swizzle: 512 blocks, each XCD gets 64 consecutive swz =
  // 8 row-tiles x 8 cols => Ohi panel 2 MB + W 2 MB per XCD L2.
  const int d = blockIdx.x;
  const int swz = (d & 7) * 64 + (d >> 3);
  const int row0 = (swz >> 3) * 128;
  const int col0 = (swz & 7) * 128;

  const int t = threadIdx.x;
  const int w = t >> 6, L = t & 63;
  const int m = L & 15, g = L >> 4;

  __shared__ __align__(16) bf16_t Ahi_s[2][128 * 64];
  __shared__ __align__(16) bf16_t Whi_s[2][128 * 64];

  f32x4 acc[4][4];
#pragma unroll
  for (int i = 0; i < 4; ++i)
#pragma unroll
    for (int j = 0; j < 4; ++j) acc[i][j] = (f32x4){0.f, 0.f, 0.f, 0.f};

  const int aw0 = (w & 1) * 64;
  const int bw0 = (w >> 1) * 64;

  int srow[4], scol[4];
#pragma unroll
  for (int i = 0; i < 4; ++i) {
    int slot = i * 256 + t;
    srow[i] = slot >> 3;
    scol[i] = (slot & 7) ^ (srow[i] & 7);
  }

#define OSTAGE(buf, k0)                                                        \
  do {                                                                         \
    _Pragma("unroll")                                                          \
    for (int i = 0; i < 4; ++i) {                                              \
      gll16(&Ahi[(size_t)(row0 + srow[i]) * D_ + (k0) + scol[i] * 8],          \
            &Ahi_s[buf][i * 2048 + w * 512]);                                  \
      gll16(&WHi[(size_t)(col0 + srow[i]) * D_ + (k0) + scol[i] * 8],          \
            &Whi_s[buf][i * 2048 + w * 512]);                                  \
    }                                                                          \
  } while (0)

  OSTAGE(0, 0);  // 8 loads in flight

  for (int kt = 0; kt < 16; ++kt) {
    const int c = kt & 1;
    if (kt < 15) {
      OSTAGE(c ^ 1, (kt + 1) * 64);  // 16 in flight (8 old + 8 new)
      asm volatile("s_waitcnt vmcnt(8)" ::: "memory");  // old 8 done
    } else {
      asm volatile("s_waitcnt vmcnt(0)" ::: "memory");
    }
    __builtin_amdgcn_s_barrier();

    const bf16_t* as_b = &Ahi_s[c][0];
    const bf16_t* ws_b = &Whi_s[c][0];
#pragma unroll
    for (int kh = 0; kh < 2; ++kh) {
      bf16x8 ah[4], wh[4];
#pragma unroll
      for (int it = 0; it < 4; ++it) {
        int row = aw0 + it * 16 + m;
        int sl = ((kh * 4 + g) ^ (m & 7)) * 8;
        ah[it] = *(const bf16x8*)&as_b[row * 64 + sl];
      }
#pragma unroll
      for (int jt = 0; jt < 4; ++jt) {
        int n = bw0 + jt * 16 + m;
        int sl = ((kh * 4 + g) ^ (m & 7)) * 8;
        wh[jt] = *(const bf16x8*)&ws_b[n * 64 + sl];
      }
#pragma unroll
      for (int it = 0; it < 4; ++it)
#pragma unroll
        for (int jt = 0; jt < 4; ++jt)
          acc[it][jt] = mfma32(ah[it], wh[jt], acc[it][jt]);
    }
    __builtin_amdgcn_s_barrier();  // all waves done reading buf c
  }
#undef OSTAGE

#pragma unroll
  for (int jt = 0; jt < 4; ++jt) {
    int col = col0 + bw0 + jt * 16 + m;
    float bcol = bias[col];
#pragma unroll
    for (int it = 0; it < 4; ++it)
#pragma unroll
      for (int r = 0; r < 4; ++r) {
        int row = row0 + aw0 + it * 16 + g * 4 + r;
        Out[(size_t)row * D_ + col] = acc[it][jt][r] + bcol;
      }
  }
}

// ---------------------------------------------------------------------------
extern "C" void kernel_launch(void* const* d_in, const int* in_sizes, int n_in,
                              void* d_out, int out_size, void* d_ws, size_t ws_size,
                              hipStream_t stream) {
  const float* q  = (const float*)d_in[0];
  const float* k  = (const float*)d_in[1];
  const float* v  = (const float*)d_in[2];
  const float* wq = (const float*)d_in[3];
  const float* bq = (const float*)d_in[4];
  const float* wk = (const float*)d_in[5];
  const float* bk = (const float*)d_in[6];
  const float* wv = (const float*)d_in[7];
  const float* bv = (const float*)d_in[8];
  const float* wo = (const float*)d_in[9];
  const float* bo = (const float*)d_in[10];
  float* out = (float*)d_out;

  char* ws = (char*)d_ws;
  bf16_t* wtHi = (bf16_t*)(ws);                      // 8 MB
  bf16_t* QKVh = (bf16_t*)(ws + (8ull << 20));       // 48 MB (Qh, Kh, VhT)
  bf16_t* Ohi  = (bf16_t*)(ws + (56ull << 20));      // 16 MB
  bf16_t* Abf  = (bf16_t*)(ws + (56ull << 20));      // 48 MB (overlaps Ohi)

  const bool big = ws_size >= (104ull << 20);

  if (big) {
    hipLaunchKernelGGL(prep_all, dim3(25600), dim3(256), 0, stream,
                       q, k, v, wq, wk, wv, wo, wtHi, Abf);
    hipLaunchKernelGGL(gemm_qkv_bf16, dim3(1536), dim3(256), 0, stream,
                       Abf, bq, bk, bv, wtHi, QKVh);
  } else {
    hipLaunchKernelGGL(prep_all, dim3(1024), dim3(256), 0, stream,
                       q, k, v, wq, wk, wv, wo, wtHi, (bf16_t*)wtHi /*unused*/);
    hipLaunchKernelGGL(gemm_qkv_f32, dim3(64, 8, 3), dim3(256), 0, stream,
                       q, k, v, bq, bk, bv, wtHi, QKVh);
  }
  hipLaunchKernelGGL(attn, dim3(16, 64), dim3(256), 0, stream,
                     QKVh, QKVh + 8388608, QKVh + 16777216, Ohi);
  hipLaunchKernelGGL(gemm_out, dim3(512), dim3(256), 0, stream,
                     Ohi, wtHi, bo, out);
}